// Round 5
// baseline (265.437 us; speedup 1.0000x reference)
//
#include <hip/hip_runtime.h>
#include <stdint.h>

#define H 256
#define NBINS 1024         // key = ((c>>7)&7)<<7 | (r>>9): XCD-group of c, then r-region
#define NB 128             // blocks in hist/scatter (each owns E/NB contiguous edges)
#define SCAN_T 1024        // PER = NBINS*NB/SCAN_T = 128 = NB (thread t owns bin t)

typedef __bf16 bf16x8 __attribute__((ext_vector_type(8)));
typedef float  f32x4  __attribute__((ext_vector_type(4)));

__device__ __forceinline__ unsigned short f2bf(float f) {
  unsigned u = __builtin_bit_cast(unsigned, f);
  u += 0x7FFFu + ((u >> 16) & 1u);            // round-to-nearest-even
  return (unsigned short)(u >> 16);
}
__device__ __forceinline__ float bflo(unsigned u){ return __builtin_bit_cast(float, u << 16); }
__device__ __forceinline__ float bfhi(unsigned u){ return __builtin_bit_cast(float, u & 0xFFFF0000u); }

__device__ __forceinline__ void g2l16(const void* g, void* l) {
  __builtin_amdgcn_global_load_lds((__attribute__((address_space(1))) void*)g,
                                   (__attribute__((address_space(3))) void*)l, 16, 0, 0);
}

// primary: XCD-affinity group from c (c-partition 3.1 MB/XCD, L2-resident — R4-verified);
// secondary: r-region (512 nodes) so r-misses sweep quasi-sequentially.
__device__ __forceinline__ int skey_of(int c, int r) {
  return (((c >> 7) & 7) << 7) | (r >> 9);
}

// ---- launch 1: fp32->bf16 conversions (blocks >= NB) + edge histogram (blocks < NB) ----
__global__ __launch_bounds__(256) void prep_kernel(
    const float* __restrict__ emb, const float* __restrict__ W1, const float* __restrict__ W2,
    const int* __restrict__ ei, int E,
    unsigned short* __restrict__ embB, unsigned short* __restrict__ w1B,
    unsigned short* __restrict__ w2B, int NH, int MpH, float* __restrict__ ssq, int Mp,
    int* __restrict__ blockHist) {
  __shared__ int h[NBINS];
  if (blockIdx.x < NB) {
    for (int i = threadIdx.x; i < NBINS; i += 256) h[i] = 0;
    __syncthreads();
    const int chunk = (E + NB - 1) / NB;
    const int start = blockIdx.x * chunk, end = min(E, start + chunk);
    for (int e = start + threadIdx.x; e < end; e += 256)
      atomicAdd(&h[skey_of(ei[e], ei[E + e])], 1);
    __syncthreads();
    for (int i = threadIdx.x; i < NBINS; i += 256)
      blockHist[i * NB + blockIdx.x] = h[i];
    return;
  }
  int t = (blockIdx.x - NB) * 256 + threadIdx.x;
  if (t < Mp) ssq[t] = 0.f;
  int i = t * 4;
  const int HH = H * H;
  const float* src; unsigned short* dst; int idx; int valid;
  if (i < MpH)            { src = emb; dst = embB; idx = i;            valid = NH; }
  else if (i < MpH + HH)  { src = W1;  dst = w1B;  idx = i - MpH;      valid = HH; }
  else                    { src = W2;  dst = w2B;  idx = i - MpH - HH; valid = HH; }
  float4 v = make_float4(0.f, 0.f, 0.f, 0.f);
  if (idx < valid) v = *(const float4*)(src + idx);
  ushort4 o;
  o.x = f2bf(v.x); o.y = f2bf(v.y); o.z = f2bf(v.z); o.w = f2bf(v.w);
  *(ushort4*)(dst + idx) = o;
}

// ---- launch 2: fused 2-layer MLP. Block = 64 rows x full 256 cols, 4 waves (64x64 each).
// g = (relu(A@W1^T + b1)) @ W2^T + b2, bf16 in/out, fp32 accum, h via padded LDS.
// Also accumulates per-row ssq of g.
__global__ __launch_bounds__(256) void mlp_fused_kernel(
    const unsigned short* __restrict__ A,
    const unsigned short* __restrict__ W1b,
    const unsigned short* __restrict__ W2b,
    const float* __restrict__ b1,
    const float* __restrict__ b2,
    unsigned short* __restrict__ G,
    float* __restrict__ ssq) {
  __shared__ unsigned short sA[64 * 32];      // 4 KB   A k-slice
  __shared__ unsigned short sW[256 * 32];     // 16 KB  W k-slice (reused W1 then W2)
  __shared__ unsigned short sH[64 * 264];     // 33 KB  h, stride 264 (pad 8: bank-safe)
  const int tid  = threadIdx.x;
  const int wave = tid >> 6, lane = tid & 63;
  const int quad = lane >> 4, l16 = lane & 15;
  const size_t bm = blockIdx.x;

  const int lrow = lane >> 2;                 // 0..15
  const int kch  = (lane & 3) * 8;            // bf16 idx of 16B chunk
  const unsigned short* gA = A + ((bm * 64 + wave * 16 + lrow) * H + kch);
  unsigned short* lA = sA + (wave * 16 + lrow) * 32 + kch;

  f32x4 acc[4][4];
#pragma unroll
  for (int i = 0; i < 4; i++)
#pragma unroll
    for (int j = 0; j < 4; j++) acc[i][j] = (f32x4){0.f, 0.f, 0.f, 0.f};

  // ---- phase 1: h = relu(A @ W1^T + b1) ----
#pragma unroll
  for (int kk = 0; kk < 8; ++kk) {
    if (kk) __syncthreads();
    g2l16(gA + kk * 32, lA);
#pragma unroll
    for (int c = 0; c < 4; c++) {
      const int wrow = c * 64 + wave * 16 + lrow;
      g2l16(W1b + wrow * H + kk * 32 + kch, sW + wrow * 32 + kch);
    }
    __syncthreads();
    bf16x8 af[4], bfr[4];
#pragma unroll
    for (int i = 0; i < 4; i++)
      af[i] = *(const bf16x8*)(sA + (i * 16 + l16) * 32 + quad * 8);
#pragma unroll
    for (int j = 0; j < 4; j++)
      bfr[j] = *(const bf16x8*)(sW + (wave * 64 + j * 16 + l16) * 32 + quad * 8);
#pragma unroll
    for (int i = 0; i < 4; i++)
#pragma unroll
      for (int j = 0; j < 4; j++)
        acc[i][j] = __builtin_amdgcn_mfma_f32_16x16x32_bf16(af[i], bfr[j], acc[i][j], 0, 0, 0);
  }

  // h epilogue -> LDS (C/D layout: col=l16, row=quad*4+reg)
#pragma unroll
  for (int j = 0; j < 4; j++) {
    const int col = wave * 64 + j * 16 + l16;
    const float bv = b1[col];
#pragma unroll
    for (int i = 0; i < 4; i++) {
#pragma unroll
      for (int r = 0; r < 4; r++) {
        const int row = i * 16 + quad * 4 + r;
        float v = fmaxf(acc[i][j][r] + bv, 0.f);
        sH[row * 264 + col] = f2bf(v);
        acc[i][j][r] = 0.f;                   // reuse accumulator for phase 2
      }
    }
  }
  __syncthreads();                            // h visible; phase-1 sW reads done

  // ---- phase 2: g = h @ W2^T + b2 ----
#pragma unroll
  for (int kk = 0; kk < 8; ++kk) {
    if (kk) __syncthreads();
#pragma unroll
    for (int c = 0; c < 4; c++) {
      const int wrow = c * 64 + wave * 16 + lrow;
      g2l16(W2b + wrow * H + kk * 32 + kch, sW + wrow * 32 + kch);
    }
    __syncthreads();
    bf16x8 af[4], bfr[4];
#pragma unroll
    for (int i = 0; i < 4; i++)
      af[i] = *(const bf16x8*)(sH + (i * 16 + l16) * 264 + kk * 32 + quad * 8);
#pragma unroll
    for (int j = 0; j < 4; j++)
      bfr[j] = *(const bf16x8*)(sW + (wave * 64 + j * 16 + l16) * 32 + quad * 8);
#pragma unroll
    for (int i = 0; i < 4; i++)
#pragma unroll
      for (int j = 0; j < 4; j++)
        acc[i][j] = __builtin_amdgcn_mfma_f32_16x16x32_bf16(af[i], bfr[j], acc[i][j], 0, 0, 0);
  }

  // final epilogue: bias, store g, per-row ssq
  float p[4][4];
#pragma unroll
  for (int i = 0; i < 4; i++)
#pragma unroll
    for (int r = 0; r < 4; r++) p[i][r] = 0.f;
#pragma unroll
  for (int j = 0; j < 4; j++) {
    const int col = wave * 64 + j * 16 + l16;
    const float bv = b2[col];
#pragma unroll
    for (int i = 0; i < 4; i++) {
#pragma unroll
      for (int r = 0; r < 4; r++) {
        const int row = i * 16 + quad * 4 + r;
        float v = acc[i][j][r] + bv;
        p[i][r] += v * v;
        G[(bm * 64 + row) * H + col] = f2bf(v);
      }
    }
  }
#pragma unroll
  for (int i = 0; i < 4; i++) {
#pragma unroll
    for (int r = 0; r < 4; r++) {
      float s = p[i][r];
#pragma unroll
      for (int off = 1; off < 16; off <<= 1) s += __shfl_xor(s, off, 64);
      if (l16 == 0) atomicAdd(&ssq[bm * 64 + i * 16 + quad * 4 + r], s);
    }
  }
}

// ---- launch 3: parallel scan. Thread t owns bin t's NB=128 entries (PER==NB). ----
__global__ __launch_bounds__(SCAN_T) void scan_kernel(
    const int* __restrict__ blockHist, int* __restrict__ blockCur,
    int* __restrict__ offsets) {
  __shared__ int s[SCAN_T];
  const int t = threadIdx.x;
  const int base = t * NB;
  int sum = 0;
#pragma unroll
  for (int j = 0; j < NB; j += 4) {
    int4 v = *(const int4*)(blockHist + base + j);
    sum += v.x + v.y + v.z + v.w;
  }
  s[t] = sum;
  __syncthreads();
#pragma unroll
  for (int d = 1; d < SCAN_T; d <<= 1) {
    int v = (t >= d) ? s[t - d] : 0;
    __syncthreads();
    s[t] += v;
    __syncthreads();
  }
  int run = s[t] - sum;                        // exclusive base of bin t
  offsets[t] = run;
  if (t == SCAN_T - 1) offsets[NBINS] = s[t];
#pragma unroll
  for (int j = 0; j < NB; j += 4) {
    int4 v = *(const int4*)(blockHist + base + j);
    int4 o;
    o.x = run; run += v.x;
    o.y = run; run += v.y;
    o.z = run; run += v.z;
    o.w = run; run += v.w;
    *(int4*)(blockCur + base + j) = o;
  }
}

// ---- launch 4: scatter with LDS cursors (disjoint output ranges per block) ----
__global__ __launch_bounds__(256) void scatter_kernel(
    const int* __restrict__ ei, int E, const int* __restrict__ blockCur,
    int4* __restrict__ sorted) {
  __shared__ int cur[NBINS];
  for (int i = threadIdx.x; i < NBINS; i += 256)
    cur[i] = blockCur[i * NB + blockIdx.x];
  __syncthreads();
  const int chunk = (E + NB - 1) / NB;
  const int start = blockIdx.x * chunk, end = min(E, start + chunk);
  for (int e = start + threadIdx.x; e < end; e += 256) {
    int c = ei[e], r = ei[E + e];
    int pos = atomicAdd(&cur[skey_of(c, r)], 1);
    sorted[pos] = make_int4(c, r, e, 0);
  }
}

// ---- launch 5: one wave per 4 edges; grp = XCD-affinity from c; r ascending in-group ----
__global__ __launch_bounds__(256) void edge_cos_kernel(
    const int4* __restrict__ sorted, const int* __restrict__ offsets,
    const unsigned short* __restrict__ g, const float* __restrict__ ssq,
    float* __restrict__ out) {
  const int lane = threadIdx.x & 63;
  const int wave = threadIdx.x >> 6;
  const int grp  = blockIdx.x & 7;
  const int wgw  = ((blockIdx.x >> 3) << 2) + wave;   // 0..1023 within group
  const int gs = offsets[grp << 7];
  const int ge = offsets[(grp + 1) << 7];

  for (int e0 = gs + wgw * 4; e0 < ge; e0 += 4096) {
    const int nv = min(4, ge - e0);
    int4 ed[4];
#pragma unroll
    for (int u = 0; u < 4; u++)
      ed[u] = (u < nv) ? sorted[e0 + u] : make_int4(0, 0, 0, 0);

    uint2 va[4], vb[4];
#pragma unroll
    for (int u = 0; u < 4; u++) {
      va[u] = ((const uint2*)(g + (size_t)ed[u].x * H))[lane];
      vb[u] = ((const uint2*)(g + (size_t)ed[u].y * H))[lane];
    }
    float d0, d1, d2, d3;
    float* dp[4] = {&d0, &d1, &d2, &d3};
#pragma unroll
    for (int u = 0; u < 4; u++) {
      uint2 a = va[u], b = vb[u];
      *dp[u] = bflo(a.x) * bflo(b.x) + bfhi(a.x) * bfhi(b.x) +
               bflo(a.y) * bflo(b.y) + bfhi(a.y) * bfhi(b.y);
    }
#pragma unroll
    for (int off = 1; off < 64; off <<= 1) {
      d0 += __shfl_xor(d0, off, 64);
      d1 += __shfl_xor(d1, off, 64);
      d2 += __shfl_xor(d2, off, 64);
      d3 += __shfl_xor(d3, off, 64);
    }
    if (lane == 0 && 0 < nv)
      out[ed[0].z] = d0 * rsqrtf(fmaxf(ssq[ed[0].x], 1e-16f)) * rsqrtf(fmaxf(ssq[ed[0].y], 1e-16f));
    if (lane == 1 && 1 < nv)
      out[ed[1].z] = d1 * rsqrtf(fmaxf(ssq[ed[1].x], 1e-16f)) * rsqrtf(fmaxf(ssq[ed[1].y], 1e-16f));
    if (lane == 2 && 2 < nv)
      out[ed[2].z] = d2 * rsqrtf(fmaxf(ssq[ed[2].x], 1e-16f)) * rsqrtf(fmaxf(ssq[ed[2].y], 1e-16f));
    if (lane == 3 && 3 < nv)
      out[ed[3].z] = d3 * rsqrtf(fmaxf(ssq[ed[3].x], 1e-16f)) * rsqrtf(fmaxf(ssq[ed[3].y], 1e-16f));
  }
}

extern "C" void kernel_launch(void* const* d_in, const int* in_sizes, int n_in,
                              void* d_out, int out_size, void* d_ws, size_t ws_size,
                              hipStream_t stream) {
  const float* emb = (const float*)d_in[0];
  const int*   ei  = (const int*)d_in[1];
  const float* W1  = (const float*)d_in[2];
  const float* b1  = (const float*)d_in[3];
  const float* W2  = (const float*)d_in[4];
  const float* b2  = (const float*)d_in[5];
  float* out = (float*)d_out;

  const int NH = in_sizes[0];
  const int N  = NH / H;
  const int E  = in_sizes[1] / 2;
  const int Mp = ((N + 63) / 64) * 64;        // 50048 (64-row GEMM blocks)
  const int MpH = Mp * H;
  const int HH  = H * H;

  char* ws = (char*)d_ws;
  unsigned short* embB = (unsigned short*)ws; ws += (size_t)MpH * 2;
  unsigned short* gB   = (unsigned short*)ws; ws += (size_t)MpH * 2;
  unsigned short* w1B  = (unsigned short*)ws; ws += (size_t)HH * 2;
  unsigned short* w2B  = (unsigned short*)ws; ws += (size_t)HH * 2;
  float* ssq           = (float*)ws;          ws += (size_t)Mp * 4;
  int* offsets         = (int*)ws;            ws += (NBINS + 1) * 4;
  int* blockHist       = (int*)ws;            ws += NBINS * NB * 4;
  int* blockCur        = (int*)ws;            ws += NBINS * NB * 4;
  int4* sorted         = (int4*)ws;           ws += (size_t)E * 16;

  const int convBlocks = (MpH + 2 * HH) / 4 / 256;   // exact: MpH,HH divisible by 1024
  prep_kernel<<<NB + convBlocks, 256, 0, stream>>>(
      emb, W1, W2, ei, E, embB, w1B, w2B, NH, MpH, ssq, Mp, blockHist);

  mlp_fused_kernel<<<Mp / 64, 256, 0, stream>>>(embB, w1B, w2B, b1, b2, gB, ssq);

  scan_kernel<<<1, SCAN_T, 0, stream>>>(blockHist, blockCur, offsets);
  scatter_kernel<<<NB, 256, 0, stream>>>(ei, E, blockCur, sorted);

  edge_cos_kernel<<<2048, 256, 0, stream>>>(sorted, offsets, gB, ssq, out);
}

// Round 6
// 214.878 us; speedup vs baseline: 1.2353x; 1.2353x over previous
//
#include <hip/hip_runtime.h>
#include <stdint.h>

#define H 256
#define NBINS 512          // skey: b=c>>7; ((b&7)<<6)|(b>>3)  (c-side XCD-affinity, R4-proven)
#define NB 128             // blocks in hist/scatter (each owns E/NB contiguous edges)
#define SCAN_T 1024        // PER = NBINS*NB/SCAN_T = 64 ints per thread

typedef __bf16 bf16x8 __attribute__((ext_vector_type(8)));
typedef float  f32x4  __attribute__((ext_vector_type(4)));

__device__ __forceinline__ unsigned short f2bf(float f) {
  unsigned u = __builtin_bit_cast(unsigned, f);
  u += 0x7FFFu + ((u >> 16) & 1u);            // round-to-nearest-even
  return (unsigned short)(u >> 16);
}

__device__ __forceinline__ void g2l16(const void* g, void* l) {
  __builtin_amdgcn_global_load_lds((__attribute__((address_space(1))) void*)g,
                                   (__attribute__((address_space(3))) void*)l, 16, 0, 0);
}

__device__ __forceinline__ int skey_of(int c) {
  int b = c >> 7;
  return ((b & 7) << 6) | (b >> 3);
}

// ---- launch 1: fp32->bf16 conversions (blocks >= NB) + edge histogram (blocks < NB) ----
__global__ __launch_bounds__(256) void prep_kernel(
    const float* __restrict__ emb, const float* __restrict__ W1, const float* __restrict__ W2,
    const int* __restrict__ ei, int E,
    unsigned short* __restrict__ embB, unsigned short* __restrict__ w1B,
    unsigned short* __restrict__ w2B, int NH, int MpH, float* __restrict__ ssq, int Mp,
    int* __restrict__ blockHist) {
  __shared__ int h[NBINS];
  if (blockIdx.x < NB) {
    for (int i = threadIdx.x; i < NBINS; i += 256) h[i] = 0;
    __syncthreads();
    const int chunk = (E + NB - 1) / NB;
    const int start = blockIdx.x * chunk, end = min(E, start + chunk);
    for (int e = start + threadIdx.x; e < end; e += 256)
      atomicAdd(&h[skey_of(ei[e])], 1);
    __syncthreads();
    for (int i = threadIdx.x; i < NBINS; i += 256)
      blockHist[i * NB + blockIdx.x] = h[i];
    return;
  }
  int t = (blockIdx.x - NB) * 256 + threadIdx.x;
  if (t < Mp) ssq[t] = 0.f;
  int i = t * 4;
  const int HH = H * H;
  const float* src; unsigned short* dst; int idx; int valid;
  if (i < MpH)            { src = emb; dst = embB; idx = i;            valid = NH; }
  else if (i < MpH + HH)  { src = W1;  dst = w1B;  idx = i - MpH;      valid = HH; }
  else                    { src = W2;  dst = w2B;  idx = i - MpH - HH; valid = HH; }
  float4 v = make_float4(0.f, 0.f, 0.f, 0.f);
  if (idx < valid) v = *(const float4*)(src + idx);
  ushort4 o;
  o.x = f2bf(v.x); o.y = f2bf(v.y); o.z = f2bf(v.z); o.w = f2bf(v.w);
  *(ushort4*)(dst + idx) = o;
}

// C[Mp,256] = act(A[Mp,256] @ B[256,256]^T + bias), bf16 in/out, fp32 accum.
// R4-proven 128x128 structure. NORM: accumulate per-row ssq of outputs.
template<bool RELU, bool NORM>
__global__ __launch_bounds__(256) void gemm_bt_kernel(
    const unsigned short* __restrict__ A,
    const unsigned short* __restrict__ B,
    const float* __restrict__ bias,
    unsigned short* __restrict__ C,
    float* __restrict__ ssq) {
  __shared__ unsigned short sA[128 * 32];
  __shared__ unsigned short sB[128 * 32];
  const int tid  = threadIdx.x;
  const int wave = tid >> 6, lane = tid & 63;
  const int quad = lane >> 4, l16 = lane & 15;
  const int wm = wave & 1, wn = wave >> 1;
  const size_t bm = blockIdx.x, bn = blockIdx.y;

  const int srow0 = (wave * 2 + 0) * 16 + (lane >> 2);
  const int srow1 = (wave * 2 + 1) * 16 + (lane >> 2);
  const int kch   = (lane & 3) * 8;
  const unsigned short* gA0 = A + ((bm * 128 + srow0) * H + kch);
  const unsigned short* gA1 = A + ((bm * 128 + srow1) * H + kch);
  const unsigned short* gB0 = B + ((bn * 128 + srow0) * H + kch);
  const unsigned short* gB1 = B + ((bn * 128 + srow1) * H + kch);
  unsigned short* lA0 = sA + (wave * 2 + 0) * 512 + lane * 8;
  unsigned short* lA1 = sA + (wave * 2 + 1) * 512 + lane * 8;
  unsigned short* lB0 = sB + (wave * 2 + 0) * 512 + lane * 8;
  unsigned short* lB1 = sB + (wave * 2 + 1) * 512 + lane * 8;

  f32x4 acc[4][4];
#pragma unroll
  for (int i = 0; i < 4; i++)
#pragma unroll
    for (int j = 0; j < 4; j++) acc[i][j] = (f32x4){0.f, 0.f, 0.f, 0.f};

#pragma unroll
  for (int kk = 0; kk < H / 32; ++kk) {
    const int k0 = kk * 32;
    if (kk) __syncthreads();
    g2l16(gA0 + k0, lA0);
    g2l16(gA1 + k0, lA1);
    g2l16(gB0 + k0, lB0);
    g2l16(gB1 + k0, lB1);
    __syncthreads();

    bf16x8 af[4], bfr[4];
#pragma unroll
    for (int i = 0; i < 4; i++)
      af[i] = *(const bf16x8*)(sA + ((wm * 64 + i * 16 + l16) * 32 + quad * 8));
#pragma unroll
    for (int j = 0; j < 4; j++)
      bfr[j] = *(const bf16x8*)(sB + ((wn * 64 + j * 16 + l16) * 32 + quad * 8));
#pragma unroll
    for (int i = 0; i < 4; i++)
#pragma unroll
      for (int j = 0; j < 4; j++)
        acc[i][j] = __builtin_amdgcn_mfma_f32_16x16x32_bf16(af[i], bfr[j], acc[i][j], 0, 0, 0);
  }

  const int row_base = (int)bm * 128 + wm * 64;
  const int col_base = (int)bn * 128 + wn * 64;
  float p[4][4];
  if (NORM) {
#pragma unroll
    for (int i = 0; i < 4; i++)
#pragma unroll
      for (int r = 0; r < 4; r++) p[i][r] = 0.f;
  }
#pragma unroll
  for (int j = 0; j < 4; j++) {
    const int col = col_base + j * 16 + l16;
    const float bv = bias[col];
#pragma unroll
    for (int i = 0; i < 4; i++) {
#pragma unroll
      for (int r = 0; r < 4; r++) {
        const int row = row_base + i * 16 + quad * 4 + r;
        float v = acc[i][j][r] + bv;
        if (RELU) v = fmaxf(v, 0.f);
        if (NORM) p[i][r] += v * v;
        C[(size_t)row * H + col] = f2bf(v);
      }
    }
  }
  if (NORM) {
#pragma unroll
    for (int i = 0; i < 4; i++) {
#pragma unroll
      for (int r = 0; r < 4; r++) {
        float s = p[i][r];
#pragma unroll
        for (int off = 1; off < 16; off <<= 1) s += __shfl_xor(s, off, 64);
        if (l16 == 0) atomicAdd(&ssq[row_base + i * 16 + quad * 4 + r], s);
      }
    }
  }
}

// ---- parallel scan over flat [NBINS*NB] histogram (R4-proven) ----
__global__ __launch_bounds__(SCAN_T) void scan_kernel(
    const int* __restrict__ blockHist, int* __restrict__ blockCur,
    int* __restrict__ offsets) {
  __shared__ int s[SCAN_T];
  const int t = threadIdx.x;
  const int PER = NBINS * NB / SCAN_T;         // 64
  const int base = t * PER;
  int sum = 0;
#pragma unroll
  for (int j = 0; j < PER; j += 4) {
    int4 v = *(const int4*)(blockHist + base + j);
    sum += v.x + v.y + v.z + v.w;
  }
  s[t] = sum;
  __syncthreads();
#pragma unroll
  for (int d = 1; d < SCAN_T; d <<= 1) {
    int v = (t >= d) ? s[t - d] : 0;
    __syncthreads();
    s[t] += v;
    __syncthreads();
  }
  int run = s[t] - sum;
  if (t == SCAN_T - 1) offsets[NBINS] = s[t];
  if ((base % NB) == 0) offsets[base / NB] = run;
#pragma unroll
  for (int j = 0; j < PER; j += 4) {
    int4 v = *(const int4*)(blockHist + base + j);
    int4 o;
    o.x = run; run += v.x;
    o.y = run; run += v.y;
    o.z = run; run += v.z;
    o.w = run; run += v.w;
    *(int4*)(blockCur + base + j) = o;
  }
}

__global__ __launch_bounds__(256) void scatter_kernel(
    const int* __restrict__ ei, int E, const int* __restrict__ blockCur,
    int4* __restrict__ sorted) {
  __shared__ int cur[NBINS];
  for (int i = threadIdx.x; i < NBINS; i += 256)
    cur[i] = blockCur[i * NB + blockIdx.x];
  __syncthreads();
  const int chunk = (E + NB - 1) / NB;
  const int start = blockIdx.x * chunk, end = min(E, start + chunk);
  for (int e = start + threadIdx.x; e < end; e += 256) {
    int c = ei[e], r = ei[E + e];
    int pos = atomicAdd(&cur[skey_of(c)], 1);   // LDS atomic; disjoint ranges per block
    sorted[pos] = make_int4(c, r, e, 0);
  }
}

// ---- edge dots via MFMA diagonal: one wave = 16 edges/tile, no LDS, no shuffles ----
// A-frag: lane holds g[c_{l16}][quad*8 .. +8); B-frag: g[r_{l16}][quad*8 .. +8).
// D[m][n] = dot(g[c_m], g[r_n]); diagonal m==n = the 16 edge dots.
// C/D layout (m89/m91): col=l16, row=quad*4+reg -> lane with quad==l16>>2 owns diag elem reg=l16&3.
__global__ __launch_bounds__(256) void edge_mfma_kernel(
    const int4* __restrict__ sorted, const int* __restrict__ offsets,
    const unsigned short* __restrict__ g, const float* __restrict__ ssq,
    float* __restrict__ out) {
  const int lane = threadIdx.x & 63;
  const int wave = threadIdx.x >> 6;
  const int l16 = lane & 15, quad = lane >> 4;
  const int grp = blockIdx.x & 7;                    // XCD-affinity group
  const int wgw = ((blockIdx.x >> 3) << 2) + wave;   // 0..1023 within group
  const int gs = offsets[grp << 6];
  const int ge = offsets[(grp + 1) << 6];
  const bool diag = (quad == (l16 >> 2));

  for (int t0 = gs + wgw * 16; t0 < ge; t0 += 1024 * 16) {
    const int4 ed = sorted[min(t0 + l16, ge - 1)];
    const unsigned short* pa = g + (size_t)ed.x * H + quad * 8;
    const unsigned short* pb = g + (size_t)ed.y * H + quad * 8;
    f32x4 acc = (f32x4){0.f, 0.f, 0.f, 0.f};
#pragma unroll
    for (int kk = 0; kk < 8; kk++) {
      bf16x8 a = *(const bf16x8*)(pa + kk * 32);
      bf16x8 b = *(const bf16x8*)(pb + kk * 32);
      acc = __builtin_amdgcn_mfma_f32_16x16x32_bf16(a, b, acc, 0, 0, 0);
    }
    if (diag && (t0 + l16 < ge)) {
      const int rsel = l16 & 3;
      float d = (rsel == 0) ? acc[0] : (rsel == 1) ? acc[1] : (rsel == 2) ? acc[2] : acc[3];
      out[ed.z] = d * rsqrtf(fmaxf(ssq[ed.x], 1e-16f)) * rsqrtf(fmaxf(ssq[ed.y], 1e-16f));
    }
  }
}

extern "C" void kernel_launch(void* const* d_in, const int* in_sizes, int n_in,
                              void* d_out, int out_size, void* d_ws, size_t ws_size,
                              hipStream_t stream) {
  const float* emb = (const float*)d_in[0];
  const int*   ei  = (const int*)d_in[1];
  const float* W1  = (const float*)d_in[2];
  const float* b1  = (const float*)d_in[3];
  const float* W2  = (const float*)d_in[4];
  const float* b2  = (const float*)d_in[5];
  float* out = (float*)d_out;

  const int NH = in_sizes[0];
  const int N  = NH / H;
  const int E  = in_sizes[1] / 2;
  const int Mp = ((N + 127) / 128) * 128;     // 50048
  const int MpH = Mp * H;
  const int HH  = H * H;

  char* ws = (char*)d_ws;
  unsigned short* embB = (unsigned short*)ws; ws += (size_t)MpH * 2;
  unsigned short* hB   = (unsigned short*)ws; ws += (size_t)MpH * 2;   // dead after gemm2
  unsigned short* gB   = (unsigned short*)ws; ws += (size_t)MpH * 2;
  unsigned short* w1B  = (unsigned short*)ws; ws += (size_t)HH * 2;
  unsigned short* w2B  = (unsigned short*)ws; ws += (size_t)HH * 2;
  float* ssq           = (float*)ws;          ws += (size_t)Mp * 4;
  int* offsets         = (int*)ws;            ws += (NBINS + 1) * 4;
  int* blockHist       = (int*)ws;            ws += NBINS * NB * 4;
  int* blockCur        = (int*)ws;            ws += NBINS * NB * 4;
  int4* sorted = (int4*)hB;                   // alias: hB dead once gemm2 done

  const int convBlocks = (MpH + 2 * HH) / 4 / 256;   // exact division
  prep_kernel<<<NB + convBlocks, 256, 0, stream>>>(
      emb, W1, W2, ei, E, embB, w1B, w2B, NH, MpH, ssq, Mp, blockHist);

  dim3 ggrid(Mp / 128, H / 128);
  gemm_bt_kernel<true,  false><<<ggrid, 256, 0, stream>>>(embB, w1B, b1, hB, nullptr);
  gemm_bt_kernel<false, true ><<<ggrid, 256, 0, stream>>>(hB, w2B, b2, gB, ssq);

  scan_kernel<<<1, SCAN_T, 0, stream>>>(blockHist, blockCur, offsets);
  scatter_kernel<<<NB, 256, 0, stream>>>(ei, E, blockCur, sorted);

  edge_mfma_kernel<<<2048, 256, 0, stream>>>(sorted, offsets, gB, ssq, out);
}